// Round 17
// baseline (95.278 us; speedup 1.0000x reference)
//
#include <hip/hip_runtime.h>

#define NB 8192
#define ND 256
#define NCLS 64
#define LOSS_MARGIN 0.2f
#define NEG_INF_F (-1e9f)
#define LMAXT 3
#define NBLK_LOSS (LMAXT * LMAXT * NCLS)
#define NT 64           // 8192/128 tile grid
#define NTILE_T 2080    // 64*65/2 triangular tiles

typedef __attribute__((ext_vector_type(8))) __bf16 bf16x8;
typedef __attribute__((ext_vector_type(4))) float f32x4;

// fp32 -> bf16 bits, round-to-nearest-even
__device__ __forceinline__ unsigned short f2bf(float f) {
  unsigned u = __float_as_uint(f);
  unsigned r = (u + 0x7fffu + ((u >> 16) & 1u)) >> 16;
  return (unsigned short)r;
}

// async global->LDS, 16 bytes per lane
__device__ __forceinline__ void gl_lds16(const void* gsrc, void* ldst) {
  __builtin_amdgcn_global_load_lds(
      (const __attribute__((address_space(1))) void*)gsrc,
      (__attribute__((address_space(3))) void*)ldst, 16, 0, 0);
}

// ---- class_start + stable class index list; also zero loss accumulators ----
__global__ __launch_bounds__(256) void build_idx(const int* __restrict__ aff,
                                                 int* __restrict__ class_start,
                                                 int* __restrict__ class_idx,
                                                 unsigned long long* __restrict__ acc_sum,
                                                 int* __restrict__ acc_cnt,
                                                 int* __restrict__ acc_done) {
  const int c = blockIdx.x;
  const int t = threadIdx.x;
  const int lane = t & 63, wave = t >> 6;
  __shared__ int wtotLT[4];
  __shared__ int wtotEQ[4];

  if (c == 0 && t == 0) {
    *acc_sum = 0ull;
    *acc_cnt = 0;
    *acc_done = 0;
  }

  int a[32];
#pragma unroll
  for (int k = 0; k < 32; ++k) a[k] = aff[t * 32 + k];
  int ltc = 0, meq = 0;
#pragma unroll
  for (int k = 0; k < 32; ++k) {
    ltc += (a[k] < c) ? 1 : 0;
    meq += (a[k] == c) ? 1 : 0;
  }

  int sc = meq;
  for (int d = 1; d < 64; d <<= 1) {
    int n = __shfl_up(sc, d);
    if (lane >= d) sc += n;
  }
  int ltr = ltc;
  for (int off = 32; off; off >>= 1) ltr += __shfl_down(ltr, off);
  if (lane == 63) wtotEQ[wave] = sc;
  if (lane == 0) wtotLT[wave] = ltr;
  __syncthreads();

  int base = wtotLT[0] + wtotLT[1] + wtotLT[2] + wtotLT[3];
  int wpre = 0;
  for (int w = 0; w < wave; ++w) wpre += wtotEQ[w];
  int p = base + wpre + (sc - meq);

  if (t == 0) {
    class_start[c] = base;
    if (c == 0) class_start[NCLS] = NB;
  }
#pragma unroll
  for (int k = 0; k < 32; ++k)
    if (a[k] == c) class_idx[p++] = t * 32 + k;
}

// ---- gather rows in class order, convert to bf16 (grid-wide parallel) ----
__global__ __launch_bounds__(256) void gather_convert(const float* __restrict__ P,
                                                      const int* __restrict__ aff,
                                                      const int* __restrict__ inst,
                                                      const int* __restrict__ class_idx,
                                                      unsigned short* __restrict__ Psort,
                                                      int* __restrict__ affSort,
                                                      int* __restrict__ instSort) {
  const int t = threadIdx.x;
  const int sr = blockIdx.x * 8 + (t >> 5);
  const int c = t & 31;
  const int src = class_idx[sr];
  const float4* ps = (const float4*)(P + (size_t)src * ND);
  ushort4* pd = (ushort4*)(Psort + (size_t)sr * ND);
#pragma unroll
  for (int q = 0; q < 2; ++q) {
    float4 v = ps[c + q * 32];
    ushort4 h;
    h.x = f2bf(v.x); h.y = f2bf(v.y); h.z = f2bf(v.z); h.w = f2bf(v.w);
    pd[c + q * 32] = h;
  }
  if (c == 0) {
    affSort[sr] = aff[src];
    instSort[sr] = inst[src];
  }
}

// ---- MFMA simmax: R13-exact 128x128 triangular, 2-buffer, 32KB LDS ----
__global__ __launch_bounds__(256, 4) void simmax_mfma(const unsigned short* __restrict__ Psort,
                                                      const int* __restrict__ affSort,
                                                      float* __restrict__ part) {
  int wg = blockIdx.x;
  wg = (wg & 7) * (NTILE_T / 8) + (wg >> 3);
  int bi = (int)((129.0f - sqrtf(129.0f * 129.0f - 8.0f * (float)wg)) * 0.5f);
  while (bi * 64 - bi * (bi - 1) / 2 > wg) --bi;
  while ((bi + 1) * 64 - (bi + 1) * bi / 2 <= wg) ++bi;
  const int bj = bi + (wg - (bi * 64 - bi * (bi - 1) / 2));

  __shared__ __align__(16) unsigned short smemu[16384];
  float* rowmax_s = (float*)&smemu[0];     // [128][2], overlays buffer 0 A
  float* colmax_s = (float*)&smemu[512];   // [128][2]

  const int t = threadIdx.x;
  const int lane = t & 63;
  const int wave = t >> 6;
  const int r0 = bi * 128, c0 = bj * 128;

  const bool needMask = (affSort[c0] <= affSort[r0 + 127]);

  const int wr = (wave >> 1) * 64;
  const int wc = (wave & 1) * 64;

  f32x4 acc[4][4];
#pragma unroll
  for (int m = 0; m < 4; ++m)
#pragma unroll
    for (int n = 0; n < 4; ++n) acc[m][n] = (f32x4){0.f, 0.f, 0.f, 0.f};

  const int ci0 = t, ci1 = 256 + t;
  const int kg0 = ci0 >> 7, rw0 = ci0 & 127;
  const int kg1 = ci1 >> 7, rw1 = ci1 & 127;

#define STAGE_SIM(B, KC)                                                      \
  do {                                                                        \
    gl_lds16(Psort + (size_t)(r0 + rw0) * ND + (KC) + kg0 * 8,                \
             &smemu[(B) * 4096 + ci0 * 8]);                                   \
    gl_lds16(Psort + (size_t)(c0 + rw0) * ND + (KC) + kg0 * 8,                \
             &smemu[8192 + (B) * 4096 + ci0 * 8]);                            \
    gl_lds16(Psort + (size_t)(r0 + rw1) * ND + (KC) + kg1 * 8,                \
             &smemu[(B) * 4096 + ci1 * 8]);                                   \
    gl_lds16(Psort + (size_t)(c0 + rw1) * ND + (KC) + kg1 * 8,                \
             &smemu[8192 + (B) * 4096 + ci1 * 8]);                            \
  } while (0)

  STAGE_SIM(0, 0);
  asm volatile("s_waitcnt vmcnt(0) lgkmcnt(0)" ::: "memory");
  __builtin_amdgcn_s_barrier();
  __builtin_amdgcn_sched_barrier(0);

  int cur = 0;
#pragma unroll 1
  for (int s = 0; s < 8; ++s) {
    if (s < 7) STAGE_SIM(cur ^ 1, (s + 1) * 32);
    const int kg = lane >> 4, lr = lane & 15;
    bf16x8 a[4], b[4];
#pragma unroll
    for (int m = 0; m < 4; ++m)
      a[m] = *(const bf16x8*)&smemu[cur * 4096 + (kg * 128 + wr + m * 16 + lr) * 8];
#pragma unroll
    for (int n = 0; n < 4; ++n)
      b[n] = *(const bf16x8*)&smemu[8192 + cur * 4096 + (kg * 128 + wc + n * 16 + lr) * 8];
#pragma unroll
    for (int m = 0; m < 4; ++m)
#pragma unroll
      for (int n = 0; n < 4; ++n)
        acc[m][n] = __builtin_amdgcn_mfma_f32_16x16x32_bf16(a[m], b[n], acc[m][n], 0, 0, 0);
    __builtin_amdgcn_sched_barrier(0);
    if (s < 7) {
      asm volatile("s_waitcnt vmcnt(0)" ::: "memory");
      __builtin_amdgcn_s_barrier();
      __builtin_amdgcn_sched_barrier(0);
    }
    cur ^= 1;
  }
  // all waves past the s==6 barrier: buffer 0 is dead -> reuse as scratch

  if (needMask) {
    int aj[4];
#pragma unroll
    for (int n = 0; n < 4; ++n) aj[n] = affSort[c0 + wc + n * 16 + (lane & 15)];
#pragma unroll
    for (int m = 0; m < 4; ++m) {
#pragma unroll
      for (int r = 0; r < 4; ++r) {
        const int lrow = wr + m * 16 + (lane >> 4) * 4 + r;
        const int ai = affSort[r0 + lrow];
        float rmax = NEG_INF_F;
#pragma unroll
        for (int n = 0; n < 4; ++n)
          if (aj[n] != ai) rmax = fmaxf(rmax, acc[m][n][r]);
        rmax = fmaxf(rmax, __shfl_xor(rmax, 1));
        rmax = fmaxf(rmax, __shfl_xor(rmax, 2));
        rmax = fmaxf(rmax, __shfl_xor(rmax, 4));
        rmax = fmaxf(rmax, __shfl_xor(rmax, 8));
        if ((lane & 15) == 0) rowmax_s[lrow * 2 + (wc >> 6)] = rmax;
      }
    }
    if (bi != bj) {
#pragma unroll
      for (int n = 0; n < 4; ++n) {
        const int lcol = wc + n * 16 + (lane & 15);
        float cmax = NEG_INF_F;
#pragma unroll
        for (int m = 0; m < 4; ++m) {
          const int lrb = wr + m * 16 + (lane >> 4) * 4;
#pragma unroll
          for (int r = 0; r < 4; ++r)
            if (affSort[r0 + lrb + r] != aj[n]) cmax = fmaxf(cmax, acc[m][n][r]);
        }
        cmax = fmaxf(cmax, __shfl_xor(cmax, 16));
        cmax = fmaxf(cmax, __shfl_xor(cmax, 32));
        if (lane < 16) colmax_s[lcol * 2 + (wr >> 6)] = cmax;
      }
    }
  } else {
#pragma unroll
    for (int m = 0; m < 4; ++m) {
#pragma unroll
      for (int r = 0; r < 4; ++r) {
        float rmax = fmaxf(fmaxf(acc[m][0][r], acc[m][1][r]),
                           fmaxf(acc[m][2][r], acc[m][3][r]));
        rmax = fmaxf(rmax, __shfl_xor(rmax, 1));
        rmax = fmaxf(rmax, __shfl_xor(rmax, 2));
        rmax = fmaxf(rmax, __shfl_xor(rmax, 4));
        rmax = fmaxf(rmax, __shfl_xor(rmax, 8));
        if ((lane & 15) == 0)
          rowmax_s[(wr + m * 16 + (lane >> 4) * 4 + r) * 2 + (wc >> 6)] = rmax;
      }
    }
#pragma unroll
    for (int n = 0; n < 4; ++n) {
      float cmax = NEG_INF_F;
#pragma unroll
      for (int m = 0; m < 4; ++m)
#pragma unroll
        for (int r = 0; r < 4; ++r) cmax = fmaxf(cmax, acc[m][n][r]);
      cmax = fmaxf(cmax, __shfl_xor(cmax, 16));
      cmax = fmaxf(cmax, __shfl_xor(cmax, 32));
      if (lane < 16) colmax_s[(wc + n * 16 + (lane & 15)) * 2 + (wr >> 6)] = cmax;
    }
  }
  __syncthreads();
  if (t < 128) {
    part[(size_t)bj * NB + (r0 + t)] = fmaxf(rowmax_s[t * 2], rowmax_s[t * 2 + 1]);
  } else if (bi != bj) {
    const int cc = t - 128;
    part[(size_t)bi * NB + (c0 + cc)] = fmaxf(colmax_s[cc * 2], colmax_s[cc * 2 + 1]);
  }
#undef STAGE_SIM
}

// ---- loss: within-class Gram tiles; hn folded from part; atomic finalize ----
__global__ __launch_bounds__(256, 4) void loss_mfma(const unsigned short* __restrict__ Psort,
                                                    const int* __restrict__ class_start,
                                                    const int* __restrict__ instSort,
                                                    const float* __restrict__ part,
                                                    unsigned long long* __restrict__ acc_sum,
                                                    int* __restrict__ acc_cnt,
                                                    int* __restrict__ acc_done,
                                                    float* __restrict__ out) {
  const int c = blockIdx.z;
  const int ti = blockIdx.x, tj = blockIdx.y;
  const int t = threadIdx.x;
  const int base = class_start[c];
  const int cnt = class_start[c + 1] - base;
  const int nt = (cnt + 127) >> 7;
  const bool active = (ti < nt) && (tj < nt) && (cnt < NB);

  __shared__ __align__(16) unsigned short At[2][4096];
  __shared__ __align__(16) unsigned short Bt[2][4096];
  __shared__ int instI[128], instJ[128];
  __shared__ float hnI[128];
  __shared__ float wsum[4];
  __shared__ int wcnt[4];

  const int lane = t & 63;
  const int wave = t >> 6;

  if (active) {
    if (t < 128) {
      int ri = ti * 128 + t;
      int gi = base + (ri < cnt ? ri : 0);
      instI[t] = instSort[gi];
      float m = NEG_INF_F;
#pragma unroll 16
      for (int q = 0; q < NT; ++q) m = fmaxf(m, part[(size_t)q * NB + gi]);
      hnI[t] = m;
    } else {
      int tt = t - 128;
      int rj = tj * 128 + tt;
      int gj = base + (rj < cnt ? rj : 0);
      instJ[tt] = instSort[gj];
    }

    const int wr = (wave >> 1) * 64;
    const int wc = (wave & 1) * 64;

    f32x4 acc[4][4];
#pragma unroll
    for (int m = 0; m < 4; ++m)
#pragma unroll
      for (int n = 0; n < 4; ++n) acc[m][n] = (f32x4){0.f, 0.f, 0.f, 0.f};

    const int ci0 = t, ci1 = 256 + t;
    const int kg0 = ci0 >> 7, rw0 = ci0 & 127;
    const int kg1 = ci1 >> 7, rw1 = ci1 & 127;
    const int ra0 = base + (ti * 128 + rw0 < cnt ? ti * 128 + rw0 : 0);
    const int ra1 = base + (ti * 128 + rw1 < cnt ? ti * 128 + rw1 : 0);
    const int rb0 = base + (tj * 128 + rw0 < cnt ? tj * 128 + rw0 : 0);
    const int rb1 = base + (tj * 128 + rw1 < cnt ? tj * 128 + rw1 : 0);

#define STAGE_LOSS(B, KC)                                               \
  do {                                                                  \
    gl_lds16(Psort + (size_t)ra0 * ND + (KC) + kg0 * 8, &At[B][ci0 * 8]); \
    gl_lds16(Psort + (size_t)rb0 * ND + (KC) + kg0 * 8, &Bt[B][ci0 * 8]); \
    gl_lds16(Psort + (size_t)ra1 * ND + (KC) + kg1 * 8, &At[B][ci1 * 8]); \
    gl_lds16(Psort + (size_t)rb1 * ND + (KC) + kg1 * 8, &Bt[B][ci1 * 8]); \
  } while (0)

    STAGE_LOSS(0, 0);
    asm volatile("s_waitcnt vmcnt(0) lgkmcnt(0)" ::: "memory");
    __builtin_amdgcn_s_barrier();
    __builtin_amdgcn_sched_barrier(0);

    int cur = 0;
#pragma unroll 1
    for (int s = 0; s < 8; ++s) {
      if (s < 7) STAGE_LOSS(cur ^ 1, (s + 1) * 32);
      const int kg = lane >> 4, lr = lane & 15;
      bf16x8 a[4], b[4];
#pragma unroll
      for (int m = 0; m < 4; ++m)
        a[m] = *(const bf16x8*)&At[cur][(kg * 128 + wr + m * 16 + lr) * 8];
#pragma unroll
      for (int n = 0; n < 4; ++n)
        b[n] = *(const bf16x8*)&Bt[cur][(kg * 128 + wc + n * 16 + lr) * 8];
#pragma unroll
      for (int m = 0; m < 4; ++m)
#pragma unroll
        for (int n = 0; n < 4; ++n)
          acc[m][n] = __builtin_amdgcn_mfma_f32_16x16x32_bf16(a[m], b[n], acc[m][n], 0, 0, 0);
      __builtin_amdgcn_sched_barrier(0);
      if (s < 7) {
        asm volatile("s_waitcnt vmcnt(0)" ::: "memory");
        __builtin_amdgcn_s_barrier();
        __builtin_amdgcn_sched_barrier(0);
      }
      cur ^= 1;
    }
#undef STAGE_LOSS

    float lsum = 0.f;
    int lcnt = 0;
#pragma unroll
    for (int m = 0; m < 4; ++m) {
#pragma unroll
      for (int r = 0; r < 4; ++r) {
        const int lrow = wr + m * 16 + (lane >> 4) * 4 + r;
        const int ri = ti * 128 + lrow;
        if (ri >= cnt) continue;
        const float hnv = hnI[lrow];
        const int ii = instI[lrow];
#pragma unroll
        for (int n = 0; n < 4; ++n) {
          const int lcol = wc + n * 16 + (lane & 15);
          const int rj = tj * 128 + lcol;
          if (rj < cnt && instJ[lcol] != ii) {
            lsum += fmaxf(hnv - acc[m][n][r] + LOSS_MARGIN, 0.f);
            lcnt += 1;
          }
        }
      }
    }

    for (int off = 32; off; off >>= 1) {
      lsum += __shfl_down(lsum, off);
      lcnt += __shfl_down(lcnt, off);
    }
    if (lane == 0) { wsum[wave] = lsum; wcnt[wave] = lcnt; }
    __syncthreads();
  }

  if (t == 0) {
    if (active) {
      const float bs = wsum[0] + wsum[1] + wsum[2] + wsum[3];
      const int bc = wcnt[0] + wcnt[1] + wcnt[2] + wcnt[3];
      if (bc > 0) {
        atomicAdd(acc_sum, (unsigned long long)llrintf(bs * 1048576.0f));
        atomicAdd(acc_cnt, bc);
      }
    }
    __threadfence();
    const int old = atomicAdd(acc_done, 1);
    if (old == NBLK_LOSS - 1) {
      __threadfence();
      const unsigned long long S = atomicAdd(acc_sum, 0ull);
      const int N = atomicAdd(acc_cnt, 0);
      out[0] = (N > 0) ? (float)((double)S / 1048576.0 / (double)N) : 0.0f;
    }
  }
}

extern "C" void kernel_launch(void* const* d_in, const int* in_sizes, int n_in,
                              void* d_out, int out_size, void* d_ws, size_t ws_size,
                              hipStream_t stream) {
  const float* P = (const float*)d_in[0];
  const int* aff = (const int*)d_in[1];
  const int* inst = (const int*)d_in[2];
  float* out = (float*)d_out;

  unsigned short* Psort = (unsigned short*)d_ws;              // 4 MB
  float* part = (float*)((char*)d_ws + (size_t)NB * ND * 2);  // NT*NB f32 = 2 MB
  int* ibase = (int*)((char*)part + (size_t)NT * NB * 4);
  int* class_start = ibase;                                   // NCLS+1
  int* class_idx   = ibase + NCLS + 1;                        // NB
  int* affSort     = ibase + NCLS + 1 + NB;                   // NB
  int* instSort    = ibase + NCLS + 1 + 2 * NB;               // NB
  // 8-byte aligned accumulator block
  unsigned long long* acc_sum =
      (unsigned long long*)(((uintptr_t)(ibase + NCLS + 1 + 3 * NB) + 7) & ~(uintptr_t)7);
  int* acc_cnt  = (int*)(acc_sum + 1);
  int* acc_done = acc_cnt + 1;

  build_idx<<<NCLS, 256, 0, stream>>>(aff, class_start, class_idx,
                                      acc_sum, acc_cnt, acc_done);
  gather_convert<<<NB / 8, 256, 0, stream>>>(P, aff, inst, class_idx, Psort,
                                             affSort, instSort);
  simmax_mfma<<<NTILE_T, 256, 0, stream>>>(Psort, affSort, part);
  loss_mfma<<<dim3(LMAXT, LMAXT, NCLS), 256, 0, stream>>>(Psort, class_start, instSort,
                                                          part, acc_sum, acc_cnt,
                                                          acc_done, out);
}

// Round 18
// 89.322 us; speedup vs baseline: 1.0667x; 1.0667x over previous
//
#include <hip/hip_runtime.h>

#define NB 8192
#define ND 256
#define NCLS 64
#define LOSS_MARGIN 0.2f
#define NEG_INF_F (-1e9f)
#define LMAXT 3
#define NBLK_LOSS (NCLS * LMAXT * LMAXT)
#define NT 64          // 8192/128 tile grid
#define NTILE_T 2080   // 64*65/2 triangular tiles

typedef __attribute__((ext_vector_type(8))) __bf16 bf16x8;
typedef __attribute__((ext_vector_type(4))) float f32x4;

// fp32 -> bf16 bits, round-to-nearest-even
__device__ __forceinline__ unsigned short f2bf(float f) {
  unsigned u = __float_as_uint(f);
  unsigned r = (u + 0x7fffu + ((u >> 16) & 1u)) >> 16;
  return (unsigned short)r;
}

// async global->LDS, 16 bytes per lane
__device__ __forceinline__ void gl_lds16(const void* gsrc, void* ldst) {
  __builtin_amdgcn_global_load_lds(
      (const __attribute__((address_space(1))) void*)gsrc,
      (__attribute__((address_space(3))) void*)ldst, 16, 0, 0);
}

// ---- class_start + stable class index list; 2 barriers total ----
// one block per class, 256 threads; thread t owns ordered chunk [t*32, t*32+32).
__global__ __launch_bounds__(256) void build_idx(const int* __restrict__ aff,
                                                 int* __restrict__ class_start,
                                                 int* __restrict__ class_idx) {
  const int c = blockIdx.x;
  const int t = threadIdx.x;
  const int lane = t & 63, wave = t >> 6;
  __shared__ int wtotLT[4];
  __shared__ int wtotEQ[4];

  // local counts over own 32-element chunk (order preserved)
  int a[32];
#pragma unroll
  for (int k = 0; k < 32; ++k) a[k] = aff[t * 32 + k];
  int ltc = 0, meq = 0;
#pragma unroll
  for (int k = 0; k < 32; ++k) {
    ltc += (a[k] < c) ? 1 : 0;
    meq += (a[k] == c) ? 1 : 0;
  }

  // wave-inclusive scan of meq; wave-reduce of ltc
  int sc = meq;
  for (int d = 1; d < 64; d <<= 1) {
    int n = __shfl_up(sc, d);
    if (lane >= d) sc += n;
  }
  int ltr = ltc;
  for (int off = 32; off; off >>= 1) ltr += __shfl_down(ltr, off);
  if (lane == 63) wtotEQ[wave] = sc;
  if (lane == 0) wtotLT[wave] = ltr;
  __syncthreads();

  int base = wtotLT[0] + wtotLT[1] + wtotLT[2] + wtotLT[3];
  int wpre = 0;
  for (int w = 0; w < wave; ++w) wpre += wtotEQ[w];
  int p = base + wpre + (sc - meq);

  if (t == 0) {
    class_start[c] = base;
    if (c == 0) class_start[NCLS] = NB;
  }
#pragma unroll
  for (int k = 0; k < 32; ++k)
    if (a[k] == c) class_idx[p++] = t * 32 + k;
}

// ---- gather rows in class order, convert to bf16 (grid-wide parallel) ----
__global__ __launch_bounds__(256) void gather_convert(const float* __restrict__ P,
                                                      const int* __restrict__ aff,
                                                      const int* __restrict__ inst,
                                                      const int* __restrict__ class_idx,
                                                      unsigned short* __restrict__ Psort,
                                                      int* __restrict__ affSort,
                                                      int* __restrict__ instSort) {
  const int t = threadIdx.x;
  const int sr = blockIdx.x * 8 + (t >> 5);
  const int c = t & 31;
  const int src = class_idx[sr];
  const float4* ps = (const float4*)(P + (size_t)src * ND);
  ushort4* pd = (ushort4*)(Psort + (size_t)sr * ND);
#pragma unroll
  for (int q = 0; q < 2; ++q) {
    float4 v = ps[c + q * 32];
    ushort4 h;
    h.x = f2bf(v.x); h.y = f2bf(v.y); h.z = f2bf(v.z); h.w = f2bf(v.w);
    pd[c + q * 32] = h;
  }
  if (c == 0) {
    affSort[sr] = aff[src];
    instSort[sr] = inst[src];
  }
}

// ---- MFMA simmax: R13-exact 128x128 triangular, 2-buffer, 32KB LDS ----
__global__ __launch_bounds__(256, 4) void simmax_mfma(const unsigned short* __restrict__ Psort,
                                                      const int* __restrict__ affSort,
                                                      float* __restrict__ part) {
  int wg = blockIdx.x;
  wg = (wg & 7) * (NTILE_T / 8) + (wg >> 3);
  int bi = (int)((129.0f - sqrtf(129.0f * 129.0f - 8.0f * (float)wg)) * 0.5f);
  while (bi * 64 - bi * (bi - 1) / 2 > wg) --bi;
  while ((bi + 1) * 64 - (bi + 1) * bi / 2 <= wg) ++bi;
  const int bj = bi + (wg - (bi * 64 - bi * (bi - 1) / 2));

  __shared__ __align__(16) unsigned short smemu[16384];
  float* rowmax_s = (float*)&smemu[0];     // [128][2], overlays buffer 0 A
  float* colmax_s = (float*)&smemu[512];   // [128][2]

  const int t = threadIdx.x;
  const int lane = t & 63;
  const int wave = t >> 6;
  const int r0 = bi * 128, c0 = bj * 128;

  const bool needMask = (affSort[c0] <= affSort[r0 + 127]);

  const int wr = (wave >> 1) * 64;
  const int wc = (wave & 1) * 64;

  f32x4 acc[4][4];
#pragma unroll
  for (int m = 0; m < 4; ++m)
#pragma unroll
    for (int n = 0; n < 4; ++n) acc[m][n] = (f32x4){0.f, 0.f, 0.f, 0.f};

  const int ci0 = t, ci1 = 256 + t;
  const int kg0 = ci0 >> 7, rw0 = ci0 & 127;
  const int kg1 = ci1 >> 7, rw1 = ci1 & 127;

#define STAGE_SIM(B, KC)                                                      \
  do {                                                                        \
    gl_lds16(Psort + (size_t)(r0 + rw0) * ND + (KC) + kg0 * 8,                \
             &smemu[(B) * 4096 + ci0 * 8]);                                   \
    gl_lds16(Psort + (size_t)(c0 + rw0) * ND + (KC) + kg0 * 8,                \
             &smemu[8192 + (B) * 4096 + ci0 * 8]);                            \
    gl_lds16(Psort + (size_t)(r0 + rw1) * ND + (KC) + kg1 * 8,                \
             &smemu[(B) * 4096 + ci1 * 8]);                                   \
    gl_lds16(Psort + (size_t)(c0 + rw1) * ND + (KC) + kg1 * 8,                \
             &smemu[8192 + (B) * 4096 + ci1 * 8]);                            \
  } while (0)

  STAGE_SIM(0, 0);
  asm volatile("s_waitcnt vmcnt(0) lgkmcnt(0)" ::: "memory");
  __builtin_amdgcn_s_barrier();
  __builtin_amdgcn_sched_barrier(0);

  int cur = 0;
#pragma unroll 1
  for (int s = 0; s < 8; ++s) {
    if (s < 7) STAGE_SIM(cur ^ 1, (s + 1) * 32);
    const int kg = lane >> 4, lr = lane & 15;
    bf16x8 a[4], b[4];
#pragma unroll
    for (int m = 0; m < 4; ++m)
      a[m] = *(const bf16x8*)&smemu[cur * 4096 + (kg * 128 + wr + m * 16 + lr) * 8];
#pragma unroll
    for (int n = 0; n < 4; ++n)
      b[n] = *(const bf16x8*)&smemu[8192 + cur * 4096 + (kg * 128 + wc + n * 16 + lr) * 8];
#pragma unroll
    for (int m = 0; m < 4; ++m)
#pragma unroll
      for (int n = 0; n < 4; ++n)
        acc[m][n] = __builtin_amdgcn_mfma_f32_16x16x32_bf16(a[m], b[n], acc[m][n], 0, 0, 0);
    __builtin_amdgcn_sched_barrier(0);
    if (s < 7) {
      asm volatile("s_waitcnt vmcnt(0)" ::: "memory");
      __builtin_amdgcn_s_barrier();
      __builtin_amdgcn_sched_barrier(0);
    }
    cur ^= 1;
  }
  // all waves past the s==6 barrier: buffer 0 is dead -> reuse as scratch

  if (needMask) {
    int aj[4];
#pragma unroll
    for (int n = 0; n < 4; ++n) aj[n] = affSort[c0 + wc + n * 16 + (lane & 15)];
#pragma unroll
    for (int m = 0; m < 4; ++m) {
#pragma unroll
      for (int r = 0; r < 4; ++r) {
        const int lrow = wr + m * 16 + (lane >> 4) * 4 + r;
        const int ai = affSort[r0 + lrow];
        float rmax = NEG_INF_F;
#pragma unroll
        for (int n = 0; n < 4; ++n)
          if (aj[n] != ai) rmax = fmaxf(rmax, acc[m][n][r]);
        rmax = fmaxf(rmax, __shfl_xor(rmax, 1));
        rmax = fmaxf(rmax, __shfl_xor(rmax, 2));
        rmax = fmaxf(rmax, __shfl_xor(rmax, 4));
        rmax = fmaxf(rmax, __shfl_xor(rmax, 8));
        if ((lane & 15) == 0) rowmax_s[lrow * 2 + (wc >> 6)] = rmax;
      }
    }
    if (bi != bj) {
#pragma unroll
      for (int n = 0; n < 4; ++n) {
        const int lcol = wc + n * 16 + (lane & 15);
        float cmax = NEG_INF_F;
#pragma unroll
        for (int m = 0; m < 4; ++m) {
          const int lrb = wr + m * 16 + (lane >> 4) * 4;
#pragma unroll
          for (int r = 0; r < 4; ++r)
            if (affSort[r0 + lrb + r] != aj[n]) cmax = fmaxf(cmax, acc[m][n][r]);
        }
        cmax = fmaxf(cmax, __shfl_xor(cmax, 16));
        cmax = fmaxf(cmax, __shfl_xor(cmax, 32));
        if (lane < 16) colmax_s[lcol * 2 + (wr >> 6)] = cmax;
      }
    }
  } else {
#pragma unroll
    for (int m = 0; m < 4; ++m) {
#pragma unroll
      for (int r = 0; r < 4; ++r) {
        float rmax = fmaxf(fmaxf(acc[m][0][r], acc[m][1][r]),
                           fmaxf(acc[m][2][r], acc[m][3][r]));
        rmax = fmaxf(rmax, __shfl_xor(rmax, 1));
        rmax = fmaxf(rmax, __shfl_xor(rmax, 2));
        rmax = fmaxf(rmax, __shfl_xor(rmax, 4));
        rmax = fmaxf(rmax, __shfl_xor(rmax, 8));
        if ((lane & 15) == 0)
          rowmax_s[(wr + m * 16 + (lane >> 4) * 4 + r) * 2 + (wc >> 6)] = rmax;
      }
    }
#pragma unroll
    for (int n = 0; n < 4; ++n) {
      float cmax = NEG_INF_F;
#pragma unroll
      for (int m = 0; m < 4; ++m)
#pragma unroll
        for (int r = 0; r < 4; ++r) cmax = fmaxf(cmax, acc[m][n][r]);
      cmax = fmaxf(cmax, __shfl_xor(cmax, 16));
      cmax = fmaxf(cmax, __shfl_xor(cmax, 32));
      if (lane < 16) colmax_s[(wc + n * 16 + (lane & 15)) * 2 + (wr >> 6)] = cmax;
    }
  }
  __syncthreads();
  if (t < 128) {
    part[(size_t)bj * NB + (r0 + t)] = fmaxf(rowmax_s[t * 2], rowmax_s[t * 2 + 1]);
  } else if (bi != bj) {
    const int cc = t - 128;
    part[(size_t)bi * NB + (c0 + cc)] = fmaxf(colmax_s[cc * 2], colmax_s[cc * 2 + 1]);
  }
#undef STAGE_SIM
}

// ---- reduce 64 partial maxima per row -> hn[row] (coalesced col-major) ----
__global__ __launch_bounds__(256) void hn_reduce(const float* __restrict__ part,
                                                 float* __restrict__ hn) {
  const int i = blockIdx.x * 256 + threadIdx.x;
  float m = NEG_INF_F;
#pragma unroll 16
  for (int q = 0; q < NT; ++q) m = fmaxf(m, part[(size_t)q * NB + i]);
  hn[i] = m;
}

// ---- loss: within-class Gram tiles + hinge epilogue (2-phase, R5-proven) ----
__global__ __launch_bounds__(256, 4) void loss_mfma(const unsigned short* __restrict__ Psort,
                                                    const int* __restrict__ class_start,
                                                    const int* __restrict__ instSort,
                                                    const float* __restrict__ hn,
                                                    float* __restrict__ bsum,
                                                    int* __restrict__ bcnt) {
  const int c = blockIdx.z;
  const int ti = blockIdx.x, tj = blockIdx.y;
  const int bid = (c * LMAXT + ti) * LMAXT + tj;
  const int t = threadIdx.x;
  const int base = class_start[c];
  const int cnt = class_start[c + 1] - base;
  const int nt = (cnt + 127) >> 7;
  if (ti >= nt || tj >= nt || cnt >= NB) {
    if (t == 0) { bsum[bid] = 0.f; bcnt[bid] = 0; }
    return;
  }

  __shared__ __align__(16) unsigned short At[2][4096];
  __shared__ __align__(16) unsigned short Bt[2][4096];
  __shared__ int instI[128], instJ[128];
  __shared__ float hnI[128];

  const int lane = t & 63;
  const int wave = t >> 6;

  if (t < 128) {
    int ri = ti * 128 + t;
    int gi = base + (ri < cnt ? ri : 0);
    instI[t] = instSort[gi];
    hnI[t] = hn[gi];
  } else {
    int tt = t - 128;
    int rj = tj * 128 + tt;
    int gj = base + (rj < cnt ? rj : 0);
    instJ[tt] = instSort[gj];
  }

  const int wr = (wave >> 1) * 64;
  const int wc = (wave & 1) * 64;

  f32x4 acc[4][4];
#pragma unroll
  for (int m = 0; m < 4; ++m)
#pragma unroll
    for (int n = 0; n < 4; ++n) acc[m][n] = (f32x4){0.f, 0.f, 0.f, 0.f};

  const int ci0 = t, ci1 = 256 + t;
  const int kg0 = ci0 >> 7, rw0 = ci0 & 127;
  const int kg1 = ci1 >> 7, rw1 = ci1 & 127;
  const int ra0 = base + (ti * 128 + rw0 < cnt ? ti * 128 + rw0 : 0);
  const int ra1 = base + (ti * 128 + rw1 < cnt ? ti * 128 + rw1 : 0);
  const int rb0 = base + (tj * 128 + rw0 < cnt ? tj * 128 + rw0 : 0);
  const int rb1 = base + (tj * 128 + rw1 < cnt ? tj * 128 + rw1 : 0);

#define STAGE_LOSS(B, KC)                                               \
  do {                                                                  \
    gl_lds16(Psort + (size_t)ra0 * ND + (KC) + kg0 * 8, &At[B][ci0 * 8]); \
    gl_lds16(Psort + (size_t)rb0 * ND + (KC) + kg0 * 8, &Bt[B][ci0 * 8]); \
    gl_lds16(Psort + (size_t)ra1 * ND + (KC) + kg1 * 8, &At[B][ci1 * 8]); \
    gl_lds16(Psort + (size_t)rb1 * ND + (KC) + kg1 * 8, &Bt[B][ci1 * 8]); \
  } while (0)

  STAGE_LOSS(0, 0);
  asm volatile("s_waitcnt vmcnt(0) lgkmcnt(0)" ::: "memory");
  __builtin_amdgcn_s_barrier();
  __builtin_amdgcn_sched_barrier(0);

  int cur = 0;
#pragma unroll 1
  for (int s = 0; s < 8; ++s) {
    if (s < 7) STAGE_LOSS(cur ^ 1, (s + 1) * 32);
    const int kg = lane >> 4, lr = lane & 15;
    bf16x8 a[4], b[4];
#pragma unroll
    for (int m = 0; m < 4; ++m)
      a[m] = *(const bf16x8*)&At[cur][(kg * 128 + wr + m * 16 + lr) * 8];
#pragma unroll
    for (int n = 0; n < 4; ++n)
      b[n] = *(const bf16x8*)&Bt[cur][(kg * 128 + wc + n * 16 + lr) * 8];
#pragma unroll
    for (int m = 0; m < 4; ++m)
#pragma unroll
      for (int n = 0; n < 4; ++n)
        acc[m][n] = __builtin_amdgcn_mfma_f32_16x16x32_bf16(a[m], b[n], acc[m][n], 0, 0, 0);
    __builtin_amdgcn_sched_barrier(0);
    if (s < 7) {
      asm volatile("s_waitcnt vmcnt(0)" ::: "memory");
      __builtin_amdgcn_s_barrier();
      __builtin_amdgcn_sched_barrier(0);
    }
    cur ^= 1;
  }

  float lsum = 0.f;
  int lcnt = 0;
#pragma unroll
  for (int m = 0; m < 4; ++m) {
#pragma unroll
    for (int r = 0; r < 4; ++r) {
      const int lrow = wr + m * 16 + (lane >> 4) * 4 + r;
      const int ri = ti * 128 + lrow;
      if (ri >= cnt) continue;
      const float hnv = hnI[lrow];
      const int ii = instI[lrow];
#pragma unroll
      for (int n = 0; n < 4; ++n) {
        const int lcol = wc + n * 16 + (lane & 15);
        const int rj = tj * 128 + lcol;
        if (rj < cnt && instJ[lcol] != ii) {
          lsum += fmaxf(hnv - acc[m][n][r] + LOSS_MARGIN, 0.f);
          lcnt += 1;
        }
      }
    }
  }

  for (int off = 32; off; off >>= 1) {
    lsum += __shfl_down(lsum, off);
    lcnt += __shfl_down(lcnt, off);
  }
  __shared__ float wsum[4];
  __shared__ int wcnt[4];
  if (lane == 0) { wsum[wave] = lsum; wcnt[wave] = lcnt; }
  __syncthreads();
  if (t == 0) {
    bsum[bid] = wsum[0] + wsum[1] + wsum[2] + wsum[3];
    bcnt[bid] = wcnt[0] + wcnt[1] + wcnt[2] + wcnt[3];
  }
#undef STAGE_LOSS
}

// ---- final deterministic reduction -> scalar ----
__global__ __launch_bounds__(256) void finalize_kernel(const float* __restrict__ bsum,
                                                       const int* __restrict__ bcnt,
                                                       float* __restrict__ out) {
  const int t = threadIdx.x;
  float s = 0.f;
  int n = 0;
  for (int i = t; i < NBLK_LOSS; i += 256) { s += bsum[i]; n += bcnt[i]; }
  for (int off = 32; off; off >>= 1) {
    s += __shfl_down(s, off);
    n += __shfl_down(n, off);
  }
  __shared__ float wsum[4];
  __shared__ int wcnt[4];
  if ((t & 63) == 0) { wsum[t >> 6] = s; wcnt[t >> 6] = n; }
  __syncthreads();
  if (t == 0) {
    const float S = wsum[0] + wsum[1] + wsum[2] + wsum[3];
    const int N = wcnt[0] + wcnt[1] + wcnt[2] + wcnt[3];
    out[0] = (N > 0) ? (S / (float)N) : 0.0f;
  }
}

extern "C" void kernel_launch(void* const* d_in, const int* in_sizes, int n_in,
                              void* d_out, int out_size, void* d_ws, size_t ws_size,
                              hipStream_t stream) {
  const float* P = (const float*)d_in[0];
  const int* aff = (const int*)d_in[1];
  const int* inst = (const int*)d_in[2];
  float* out = (float*)d_out;

  unsigned short* Psort = (unsigned short*)d_ws;              // NB*ND bf16 = 4 MB
  float* part = (float*)((char*)d_ws + (size_t)NB * ND * 2);  // NT*NB f32 = 2 MB
  int* ibase = (int*)((char*)part + (size_t)NT * NB * 4);
  float* hn        = (float*)ibase;                           // NB
  int* class_start = ibase + NB;                              // NCLS+1
  int* class_idx   = ibase + NB + NCLS + 1;                   // NB
  int* affSort     = ibase + 2 * NB + NCLS + 1;               // NB
  int* instSort    = ibase + 3 * NB + NCLS + 1;               // NB
  float* bsum = (float*)(ibase + 4 * NB + NCLS + 1);          // NBLK_LOSS
  int* bcnt   = ibase + 4 * NB + NCLS + 1 + NBLK_LOSS;        // NBLK_LOSS

  build_idx<<<NCLS, 256, 0, stream>>>(aff, class_start, class_idx);
  gather_convert<<<NB / 8, 256, 0, stream>>>(P, aff, inst, class_idx, Psort,
                                             affSort, instSort);
  simmax_mfma<<<NTILE_T, 256, 0, stream>>>(Psort, affSort, part);
  hn_reduce<<<NB / 256, 256, 0, stream>>>(part, hn);
  loss_mfma<<<dim3(LMAXT, LMAXT, NCLS), 256, 0, stream>>>(Psort, class_start, instSort,
                                                          hn, bsum, bcnt);
  finalize_kernel<<<1, 256, 0, stream>>>(bsum, bcnt, out);
}